// Round 1
// baseline (125.795 us; speedup 1.0000x reference)
//
#include <hip/hip_runtime.h>

typedef float f32x4 __attribute__((ext_vector_type(4)));
typedef __bf16 bf16x8 __attribute__((ext_vector_type(8)));
typedef unsigned short u16x8 __attribute__((ext_vector_type(8)));
typedef unsigned short u16x4 __attribute__((ext_vector_type(4)));

__device__ __forceinline__ unsigned short f2bf(float f) {
  union { float f; unsigned u; } v; v.f = f;
  unsigned r = v.u + 0x7FFFu + ((v.u >> 16) & 1u);
  return (unsigned short)(r >> 16);
}

__device__ __forceinline__ void s2(float& a, float& b) {
  float t = fminf(a, b); b = fmaxf(a, b); a = t;
}

__device__ __forceinline__ float median9(float p0, float p1, float p2,
                                         float p3, float p4, float p5,
                                         float p6, float p7, float p8) {
  s2(p1,p2); s2(p4,p5); s2(p7,p8);
  s2(p0,p1); s2(p3,p4); s2(p6,p7);
  s2(p1,p2); s2(p4,p5); s2(p7,p8);
  s2(p0,p3); s2(p5,p8); s2(p4,p7);
  s2(p3,p6); s2(p1,p4); s2(p2,p5);
  s2(p4,p7); s2(p4,p2); s2(p6,p4);
  s2(p4,p2);
  return p4;
}

// conv_w fp32 [256][256] -> bf16 (RNE) in workspace
__global__ void wconv_k(const float* __restrict__ w, unsigned short* __restrict__ wbf) {
  int i = (blockIdx.x * 256 + threadIdx.x) * 4;
  f32x4 v = *(const f32x4*)(w + i);
  u16x4 o;
  o[0] = f2bf(v[0]); o[1] = f2bf(v[1]); o[2] = f2bf(v[2]); o[3] = f2bf(v[3]);
  *(u16x4*)(wbf + i) = o;
}

// One block = one (batch, row): all 256 out-channels x 64 pixels.
// K-loop over input channels in steps of 32.
__launch_bounds__(256, 3)
__global__ void fused_k(const float* __restrict__ x,
                        const unsigned short* __restrict__ wbf,
                        const float* __restrict__ bias,
                        float* __restrict__ out) {
  __shared__ float Xs[32][3][64];            // 24.0 KB: x rows for median
  __shared__ unsigned short At[256][40];     // 20.0 KB: W tile [o][c_local], pad 40
  __shared__ unsigned short Bt[64][40];      //  5.0 KB: med tile [px][c_local], pad 40
  __shared__ float BiasS[256];

  const int t   = threadIdx.x;
  const int blk = blockIdx.x;
  const int swz = ((blk & 7) << 8) | (blk >> 3);   // XCD-bijective swizzle (2048 = 8*256)
  const int b   = swz >> 6;
  const int r   = swz & 63;
  const int lane = t & 63;
  const int w    = t >> 6;       // wave 0..3
  const int g    = lane >> 4;    // lane group 0..3
  const int l15  = lane & 15;

  BiasS[t] = bias[t];

  const float* xb = x + ((size_t)b << 20);   // b * 256*64*64

  f32x4 acc[4][4];
  #pragma unroll
  for (int m = 0; m < 4; ++m)
    #pragma unroll
    for (int n = 0; n < 4; ++n)
      acc[m][n] = (f32x4){0.f, 0.f, 0.f, 0.f};

  for (int ks = 0; ks < 8; ++ks) {
    const int c0 = ks << 5;
    __syncthreads();   // LDS free from previous iteration's reads

    // --- stage x rows (c0..c0+31) x (r-1..r+1), zero-padded, coalesced float4 ---
    #pragma unroll
    for (int p = 0; p < 6; ++p) {
      int task  = (p << 8) + t;      // 0..1535 = 96 rows * 16 segs
      int seg   = task & 15;
      int rowid = task >> 4;
      int dr    = rowid >> 5;        // 0..2
      int ci    = rowid & 31;
      int gr    = r + dr - 1;
      f32x4 v = (f32x4){0.f, 0.f, 0.f, 0.f};
      if ((unsigned)gr < 64u)
        v = *(const f32x4*)(xb + ((size_t)(c0 + ci) << 12) + (gr << 6) + (seg << 2));
      *(f32x4*)&Xs[ci][dr][seg << 2] = v;
    }
    // --- stage W bf16 tile [256 o][32 c_local] ---
    #pragma unroll
    for (int p = 0; p < 4; ++p) {
      int task = (p << 8) + t;       // 0..1023 = 256 rows * 4 segs
      int oo   = task >> 2;
      int seg  = task & 3;
      *(u16x8*)&At[oo][seg << 3] = *(const u16x8*)(wbf + (oo << 8) + c0 + (seg << 3));
    }
    __syncthreads();

    // --- medians: px = lane (conflict-free row reads), c = w*8 + i ---
    {
      unsigned short mbuf[8];
      const int px = lane;
      #pragma unroll
      for (int i = 0; i < 8; ++i) {
        const float* rowp = &Xs[(w << 3) + i][0][0];
        float p0 = (px > 0)  ? rowp[px - 1]       : 0.f;
        float p1 =             rowp[px];
        float p2 = (px < 63) ? rowp[px + 1]       : 0.f;
        float p3 = (px > 0)  ? rowp[64 + px - 1]  : 0.f;
        float p4 =             rowp[64 + px];
        float p5 = (px < 63) ? rowp[64 + px + 1]  : 0.f;
        float p6 = (px > 0)  ? rowp[128 + px - 1] : 0.f;
        float p7 =             rowp[128 + px];
        float p8 = (px < 63) ? rowp[128 + px + 1] : 0.f;
        mbuf[i] = f2bf(median9(p0,p1,p2,p3,p4,p5,p6,p7,p8));
      }
      *(u16x8*)&Bt[px][w << 3] = *(const u16x8*)mbuf;   // single b128, c-contiguous
    }
    __syncthreads();

    // --- fragments + MFMA: wave w owns o in [w*64, w*64+64) ---
    bf16x8 a[4], bb[4];
    #pragma unroll
    for (int m = 0; m < 4; ++m)
      a[m] = __builtin_bit_cast(bf16x8, *(const u16x8*)&At[(w << 6) + (m << 4) + l15][g << 3]);
    #pragma unroll
    for (int n = 0; n < 4; ++n)
      bb[n] = __builtin_bit_cast(bf16x8, *(const u16x8*)&Bt[(n << 4) + l15][g << 3]);
    #pragma unroll
    for (int m = 0; m < 4; ++m)
      #pragma unroll
      for (int n = 0; n < 4; ++n)
        acc[m][n] = __builtin_amdgcn_mfma_f32_16x16x32_bf16(a[m], bb[n], acc[m][n], 0, 0, 0);
  }

  // --- epilogue: out = x + acc + bias ---
  #pragma unroll
  for (int m = 0; m < 4; ++m) {
    const int o = (w << 6) + (m << 4) + (g << 2);
    #pragma unroll
    for (int n = 0; n < 4; ++n) {
      const int px = (n << 4) + l15;
      const size_t base = ((((size_t)b << 8) + (size_t)o) << 12) + ((size_t)r << 6) + (size_t)px;
      #pragma unroll
      for (int q = 0; q < 4; ++q) {
        const size_t idx = base + ((size_t)q << 12);
        out[idx] = x[idx] + acc[m][n][q] + BiasS[o + q];
      }
    }
  }
}

extern "C" void kernel_launch(void* const* d_in, const int* in_sizes, int n_in,
                              void* d_out, int out_size, void* d_ws, size_t ws_size,
                              hipStream_t stream) {
  const float* x  = (const float*)d_in[0];
  const float* cw = (const float*)d_in[1];
  const float* cb = (const float*)d_in[2];
  float* out = (float*)d_out;
  unsigned short* wbf = (unsigned short*)d_ws;   // 128 KB

  hipLaunchKernelGGL(wconv_k, dim3(64), dim3(256), 0, stream, cw, wbf);
  hipLaunchKernelGGL(fused_k, dim3(2048), dim3(256), 0, stream, x, wbf, cb, out);
}